// Round 10
// baseline (338.503 us; speedup 1.0000x reference)
//
#include <hip/hip_runtime.h>
#include <hip/hip_bf16.h>
#include <math.h>

// Problem constants (fixed by setup_inputs)
#define DM 1024          // d_model
#define NS 16            // d_state
#define BSZ 8
#define LSEQ 1024
#define MROWS (BSZ*LSEQ) // 8192 token rows
#define CH 32            // scan chunk (timesteps staged per LDS buffer)
#define ROWP 36          // padded LDS row length (words), b128-aligned
#define YSP 18           // ys_p row pad (words), b64-aligned (c*72 % 8 == 0)

typedef __bf16 bf16;
typedef bf16 bf16x8 __attribute__((ext_vector_type(8)));
typedef bf16 bf16x4 __attribute__((ext_vector_type(4)));
typedef float f32x4 __attribute__((ext_vector_type(4)));
typedef float f32x2 __attribute__((ext_vector_type(2)));
typedef unsigned int u32;
typedef unsigned short u16;
typedef u32 u32x4 __attribute__((ext_vector_type(4)));

__device__ __forceinline__ void async16(const void* g, void* l) {
  __builtin_amdgcn_global_load_lds((const __attribute__((address_space(1))) void*)g,
                                   (__attribute__((address_space(3))) void*)l,
                                   16, 0, 0);
}

// packed (dt, xi) word: dt bf16 in low 16, xi bf16 in high 16
__device__ __forceinline__ float bflo(u32 u) { return __builtin_bit_cast(float, (u32)(u << 16)); }
__device__ __forceinline__ float bfhi(u32 u) { return __builtin_bit_cast(float, (u32)(u & 0xffff0000u)); }

// ---------------------------------------------------------------------------
// Fused preprocessing: weight casts + W_ig transpose + layernorm in ONE
// launch. Block ranges:
//   [0,4128)      : f32->bf16 casts (5 weight tensors, float4-granular)
//   [4128,4384)   : W_ig[:1024]^T transpose+cast (64x64 LDS tiles)
//   [4384,12576)  : layernorm, one block per token row
// ---------------------------------------------------------------------------
__global__ __launch_bounds__(256)
void preproc(const float* __restrict__ W_ig, const float* __restrict__ W_dt,
             const float* __restrict__ W_B, const float* __restrict__ W_C,
             const float* __restrict__ W_out,
             bf16* __restrict__ wmega, bf16* __restrict__ wstack,
             bf16* __restrict__ wout, bf16* __restrict__ wigT,
             const float* __restrict__ x, const float* __restrict__ ln_g,
             const float* __restrict__ ln_b, bf16* __restrict__ xnorm) {
  __shared__ float tile[64][65];     // used by transpose range only
  const int blk = blockIdx.x;
  const int t = threadIdx.x;

  if (blk < 4128) {
    int i = blk * 256 + t;           // float4 index, total 1056768
    const float* s; bf16* d; int base;
    if (i < 524288)      { s = W_ig;  d = wmega;                           base = 0; }
    else if (i < 786432) { s = W_dt;  d = wstack;                          base = 524288; }
    else if (i < 790528) { s = W_B;   d = wstack + (size_t)DM * DM;        base = 786432; }
    else if (i < 794624) { s = W_C;   d = wstack + (size_t)(DM + NS) * DM; base = 790528; }
    else                 { s = W_out; d = wout;                            base = 794624; }
    int k = i - base;
    float4 v = ((const float4*)s)[k];
    bf16x4 o;
    o.x = (bf16)v.x; o.y = (bf16)v.y; o.z = (bf16)v.z; o.w = (bf16)v.w;
    *(bf16x4*)(d + 4 * (size_t)k) = o;
  } else if (blk < 4384) {
    int tb = blk - 4128;
    const int bk = (tb & 15) * 64;
    const int bd = (tb >> 4) * 64;
    const int c4 = t & 15;
    const int r0 = t >> 4;
#pragma unroll
    for (int p = 0; p < 4; ++p) {
      int r = r0 + p * 16;
      float4 v = *(const float4*)(W_ig + (size_t)(bd + r) * 1024 + bk + c4 * 4);
      tile[r][c4 * 4 + 0] = v.x;
      tile[r][c4 * 4 + 1] = v.y;
      tile[r][c4 * 4 + 2] = v.z;
      tile[r][c4 * 4 + 3] = v.w;
    }
    __syncthreads();
#pragma unroll
    for (int p = 0; p < 4; ++p) {
      int r = r0 + p * 16;
      bf16x4 o;
      o.x = (bf16)tile[c4 * 4 + 0][r];
      o.y = (bf16)tile[c4 * 4 + 1][r];
      o.z = (bf16)tile[c4 * 4 + 2][r];
      o.w = (bf16)tile[c4 * 4 + 3][r];
      *(bf16x4*)(wigT + (size_t)(bk + r) * 1024 + bd + c4 * 4) = o;
    }
  } else {
    const size_t row = blk - 4384;
    float4 v = ((const float4*)(x + row * DM))[t];
    float s = v.x + v.y + v.z + v.w;
    float s2 = v.x*v.x + v.y*v.y + v.z*v.z + v.w*v.w;
#pragma unroll
    for (int m = 1; m < 64; m <<= 1) { s += __shfl_xor(s, m, 64); s2 += __shfl_xor(s2, m, 64); }
    __shared__ float red[8];
    int wave = t >> 6, lane = t & 63;
    if (lane == 0) { red[wave] = s; red[4 + wave] = s2; }
    __syncthreads();
    s  = red[0] + red[1] + red[2] + red[3];
    s2 = red[4] + red[5] + red[6] + red[7];
    float mu  = s * (1.f / DM);
    float var = s2 * (1.f / DM) - mu * mu;
    float inv = rsqrtf(var + 1e-5f);
    float4 gg = ((const float4*)ln_g)[t];
    float4 bb = ((const float4*)ln_b)[t];
    bf16x4 o;
    o.x = (bf16)((v.x - mu) * inv * gg.x + bb.x);
    o.y = (bf16)((v.y - mu) * inv * gg.y + bb.y);
    o.z = (bf16)((v.z - mu) * inv * gg.z + bb.z);
    o.w = (bf16)((v.w - mu) * inv * gg.w + bb.w);
    *(bf16x4*)(xnorm + row * DM + t * 4) = o;
  }
}

// ---------------------------------------------------------------------------
// MFMA bf16 GEMM: C[M,N] = A[M,K] @ W[N,K]^T. 128x128 tile.
// v4: pipeline depth 4 (4 LDS buffers of BK=32, stage-ahead 3). Counted
// vmcnt ladder 8/4/0 per K-step -- loads get ~3 compute phases (~500cy) to
// land, covering L2 latency with margin. LDS 64KB -> 2 blocks/CU (measured
// occupancy was already ~2.1 at 48KB). XOR k-chunk swizzle (0 conflicts).
// EPI==0 epilogue: tiled-16 output LDS-STAGED (R8: -20us) -- dense 2KB
// stores per (wave,j).
// ---------------------------------------------------------------------------
template <int EPI, bool SWZ>
__global__ __launch_bounds__(256)
void gemm_bf16(const bf16* __restrict__ A, const bf16* __restrict__ W, int K,
               float* __restrict__ out_f, bf16* __restrict__ out_b,
               u16* __restrict__ out_u1, u16* __restrict__ out_u2,
               const float* __restrict__ aux,
               float* __restrict__ out_f3, float* __restrict__ out_f4) {
  __shared__ bf16 As[4][128 * 32];
  __shared__ bf16 Bs[4][128 * 32];
  int tx, ty;
  if (SWZ) {
    int g = blockIdx.x;           // total = 8 XCD * 8 mloc * ntx
    int xcd = g & 7, slot = g >> 3;
    tx = slot >> 3;               // n-tile (n-major sweep within XCD)
    ty = xcd * 8 + (slot & 7);    // m-tile within this XCD's stripe
  } else {
    tx = blockIdx.x; ty = blockIdx.y;
  }
  const int tid  = threadIdx.x;
  const int wave = tid >> 6, lane = tid & 63;
  const int lr = lane & 15, quad = lane >> 4;
  const size_t arow = (size_t)ty * 128;
  const size_t brow = (size_t)tx * 128;
  f32x4 acc[4][4] = {};

  const int srl  = lane >> 2;          // row-local 0..15
  const int kg   = lane & 3;           // k-group 0..3
  const int srow = wave * 32 + srl;
  const int skc  = (kg ^ ((srl >> 1) & 3)) * 8;   // swizzled global k-offset
  const bf16* ag = A + (arow + srow) * (size_t)K + skc;
  const bf16* wg = W + (brow + srow) * (size_t)K + skc;

  const int soff = wave * 32 * 32;                       // stage slice
  const int ra   = (((wave >> 1) * 64) + lr) * 32 + ((quad ^ ((lr >> 1) & 3)) * 8);
  const int rb   = (((wave & 1)  * 64) + lr) * 32 + ((quad ^ ((lr >> 1) & 3)) * 8);

  bf16 *aw0 = &As[0][soff], *aw1 = &As[1][soff], *aw2 = &As[2][soff], *aw3 = &As[3][soff];
  bf16 *bw0 = &Bs[0][soff], *bw1 = &Bs[1][soff], *bw2 = &Bs[2][soff], *bw3 = &Bs[3][soff];
  const bf16 *ar0 = &As[0][ra], *ar1 = &As[1][ra], *ar2 = &As[2][ra], *ar3 = &As[3][ra];
  const bf16 *br0 = &Bs[0][rb], *br1 = &Bs[1][rb], *br2 = &Bs[2][rb], *br3 = &Bs[3][rb];

  auto STAGE = [&](bf16* adst, bf16* bdst, int kk) {
    async16(ag + kk,                       adst);
    async16(ag + (size_t)16 * K + kk,      adst + 16 * 32);
    async16(wg + kk,                       bdst);
    async16(wg + (size_t)16 * K + kk,      bdst + 16 * 32);
  };
  auto COMPUTE = [&](const bf16* ap, const bf16* bp) {
    bf16x8 af[4], bfr[4];
#pragma unroll
    for (int i = 0; i < 4; ++i) af[i] = *(const bf16x8*)(ap + i * 16 * 32);
#pragma unroll
    for (int j = 0; j < 4; ++j) bfr[j] = *(const bf16x8*)(bp + j * 16 * 32);
#pragma unroll
    for (int i = 0; i < 4; ++i)
#pragma unroll
      for (int j = 0; j < 4; ++j)
        acc[i][j] = __builtin_amdgcn_mfma_f32_16x16x32_bf16(af[i], bfr[j], acc[i][j], 0, 0, 0);
  };

  // prologue: buffers 0,1,2 in flight (12 VMEM ops/wave)
  STAGE(aw0, bw0, 0);
  STAGE(aw1, bw1, 32);
  STAGE(aw2, bw2, 64);
  asm volatile("s_waitcnt vmcnt(8)" ::: "memory");   // buf0's 4 landed
  __builtin_amdgcn_s_barrier();                       // everyone's buf0 landed

  // K = 1024 for all call sites
  for (int k0 = 0; k0 < K; k0 += 32) {
    const bool pf = (k0 + 96 < K);
    if (pf) STAGE(aw3, bw3, k0 + 96);    // into buf freed at iter-1's barrier
    COMPUTE(ar0, br0);                    // consume current buffer
    if (pf)              asm volatile("s_waitcnt vmcnt(8)" ::: "memory");
    else if (k0 + 64 < K) asm volatile("s_waitcnt vmcnt(4)" ::: "memory");
    else                 asm volatile("s_waitcnt vmcnt(0)" ::: "memory");
    __builtin_amdgcn_s_barrier();
    // rotate buffer roles (register moves only)
    bf16* t0;
    t0 = aw0; aw0 = aw1; aw1 = aw2; aw2 = aw3; aw3 = t0;
    t0 = bw0; bw0 = bw1; bw1 = bw2; bw2 = bw3; bw3 = t0;
    const bf16* t1;
    t1 = ar0; ar0 = ar1; ar1 = ar2; ar2 = ar3; ar3 = t1;
    t1 = br0; br0 = br1; br1 = br2; br2 = br3; br3 = t1;
  }
  // After the final barrier ALL waves completed their LDS reads -> As free.

  // Epilogue. D layout (verified m89/m91): col = lane&15, row = quad*4 + reg.
  const size_t mbase = arow + (wave >> 1) * 64;
  const size_t nbase = brow + (wave & 1) * 64;
  if (EPI == 0) {
    if (nbase < 3 * DM) {
      // xi / z / dt -> tiled-16 via LDS-staged dense 2KB stores per (wave,j)
      u16* dst; size_t gbase; bool is_dt = false;
      if (nbase < DM)            { dst = out_u1;       gbase = nbase >> 4; }
      else if (nbase < 2 * DM)   { dst = (u16*)out_b;  gbase = (nbase - DM) >> 4; }
      else                       { dst = out_u2;       gbase = (nbase - 2 * DM) >> 4; is_dt = true; }
      bf16* lds_ep = &As[0][0] + (size_t)wave * 1024;   // 2KB private slice
#pragma unroll
      for (int j = 0; j < 4; ++j) {
#pragma unroll
        for (int i = 0; i < 4; ++i)
#pragma unroll
          for (int r = 0; r < 4; ++r) {
            float v = acc[i][j][r];
            if (is_dt) {
              float tt = v + aux[nbase - 2 * DM + j * 16 + lr];
              v = (tt > 20.f) ? tt : __logf(1.f + __expf(tt));
            }
            lds_ep[(i * 16 + quad * 4 + r) * 16 + lr] = (bf16)v;
          }
        u32x4 v0 = *(u32x4*)&lds_ep[lane * 16];
        u32x4 v1 = *(u32x4*)&lds_ep[lane * 16 + 8];
        size_t off = ((gbase + j) * (size_t)MROWS + mbase + lane) * 16;
        *(u32x4*)&dst[off]     = v0;
        *(u32x4*)&dst[off + 8] = v1;
      }
    } else if (nbase < 3 * DM + 2 * NS) {   // B/C region (j==0 -> B, j==1 -> C)
#pragma unroll
      for (int i = 0; i < 4; ++i)
#pragma unroll
        for (int r = 0; r < 4; ++r) {
          size_t m = mbase + i * 16 + quad * 4 + r;
          out_f3[m * NS + lr] = acc[i][0][r];
          out_f4[m * NS + lr] = acc[i][1][r];
        }
    } // else: garbage pad columns, discard
  } else {
#pragma unroll
    for (int i = 0; i < 4; ++i)
#pragma unroll
      for (int j = 0; j < 4; ++j)
#pragma unroll
        for (int r = 0; r < 4; ++r) {
          size_t m = mbase + i * 16 + quad * 4 + r;
          size_t n = nbase + j * 16 + lr;
          float v = acc[i][j][r];
          if (EPI == 2) {
            out_f[m * DM + n] = v + aux[m * DM + n];
          } else {
            out_b[m * (size_t)DM + n] = (bf16)v;
          }
        }
  }
}

// ---------------------------------------------------------------------------
// Selective scan + fused gate, v8. Tiled-16 dt/xi/z + ys_p LDS n-reduction.
// New: (a) staging loads paired -- dt/xi as one u32 each (2 elements), B/C
// as f32x2 -- 10 -> 6 global loads per thread per chunk; (b) phase-2 reads
// ys_p rows as ds_read_b64 (YSP=18 pad keeps 8B alignment) -- halves the
// phase-2 LDS op count. LDS 50.7KB keeps 3 blocks/CU.
// ---------------------------------------------------------------------------
__global__ __launch_bounds__(256)
void scan_kernel(const u16* __restrict__ dt_b, const u16* __restrict__ xi_b,
                 const bf16* __restrict__ z_b,
                 const float* __restrict__ B_t, const float* __restrict__ C_t,
                 const float* __restrict__ A_log, const float* __restrict__ h_prev,
                 const float* __restrict__ Dvec,
                 bf16* __restrict__ ssm_out, float* __restrict__ h_final) {
  const int blk = blockIdx.x;        // 512 blocks
  const int b = blk >> 6;
  const int g = blk & 63;            // channel group
  const int d0 = g * 16;
  const int t = threadIdx.x;
  const int n = t & 15, dl = t >> 4;     // compute role: channel dl, state n
  const int d = d0 + dl;
  const float Ac2 = -__expf(A_log[d * NS + n]) * 1.44269504f;  // fold log2e
  float h = h_prev[(size_t)b * DM * NS + (size_t)d * NS + n];

  __shared__ u32   dxs[2][16][ROWP];   // packed (dt lo, xi hi): [chan][l]
  __shared__ float Bsh[2][16][ROWP];   // [n][l]
  __shared__ float Csh[2][16][ROWP];   // [n][l]
  __shared__ float ys_p[CH][16][YSP];  // per-lane h*C partials: [l][chan][n]

  const size_t base_row = (size_t)b * LSEQ;
  const size_t base16 = ((size_t)g * MROWS + base_row) * 16;
  // staging role (paired): thread t covers elements e0=2t, e1=2t+1 of the
  // 512-element chunk: row pl = t>>3, chans pc, pc+1 (pc even).
  const int pl = t >> 3, pc = (2 * t) & 15;
  // output role: channel c_a, rows l_a and l_a+16
  const int l_a = t >> 4, c_a = t & 15;
  const float Dva = Dvec[d0 + c_a];

  // --- stage chunk 0 ---
  {
    u32 D = ((const u32*)(dt_b + base16))[t];
    u32 X = ((const u32*)(xi_b + base16))[t];
    dxs[0][pc][pl]     = (D & 0xffffu) | (X << 16);
    dxs[0][pc + 1][pl] = (D >> 16) | (X & 0xffff0000u);
    size_t gB = base_row * NS;
    f32x2 B2 = ((const f32x2*)(B_t + gB))[t];
    f32x2 C2 = ((const f32x2*)(C_t + gB))[t];
    Bsh[0][pc][pl] = B2.x;  Bsh[0][pc + 1][pl] = B2.y;
    Csh[0][pc][pl] = C2.x;  Csh[0][pc + 1][pl] = C2.y;
  }
  float za = (float)z_b[base16 + t];
  float zb = (float)z_b[base16 + 256 + t];
  __syncthreads();

  for (int c = 0; c < LSEQ / CH; ++c) {
    const int cur = c & 1, nxt = cur ^ 1;
    // prefetch next chunk into registers (overlaps compute below)
    u32 pD, pX; f32x2 pB2, pC2; float pza, pzb;
    if (c + 1 < LSEQ / CH) {
      size_t off = base16 + (size_t)(c + 1) * (CH * 16);
      pD = ((const u32*)(dt_b + off))[t];
      pX = ((const u32*)(xi_b + off))[t];
      pza = (float)z_b[off + t]; pzb = (float)z_b[off + 256 + t];
      size_t gB = (base_row + (size_t)(c + 1) * CH) * NS;
      pB2 = ((const f32x2*)(B_t + gB))[t];
      pC2 = ((const f32x2*)(C_t + gB))[t];
    }
    // hot loop: 4 steps per LDS read batch; serial chain = fma only
#pragma unroll
    for (int l4 = 0; l4 < CH; l4 += 4) {
      u32x4 dx4 = *(const u32x4*)&dxs[cur][dl][l4];   // broadcast over n-lanes
      f32x4 b4  = *(const f32x4*)&Bsh[cur][n][l4];
      f32x4 c4  = *(const f32x4*)&Csh[cur][n][l4];
#pragma unroll
      for (int i = 0; i < 4; ++i) {
        float dtv = bflo(dx4[i]), xiv = bfhi(dx4[i]);
        float a = __builtin_amdgcn_exp2f(dtv * Ac2);
        h = fmaf(a, h, (dtv * xiv) * b4[i]);
        ys_p[l4 + i][dl][n] = h * c4[i];
      }
    }
    __syncthreads();
    // phase 2: sum over n (b64 reads), gate, store
    {
      const f32x2* r1 = (const f32x2*)&ys_p[l_a][c_a][0];
      const f32x2* r2 = (const f32x2*)&ys_p[l_a + 16][c_a][0];
      float s1 = 0.f, s2 = 0.f;
#pragma unroll
      for (int k = 0; k < 8; ++k) {
        f32x2 v1 = r1[k], v2 = r2[k];
        s1 += v1.x + v1.y;
        s2 += v2.x + v2.y;
      }
      float x1 = bfhi(dxs[cur][c_a][l_a]);
      float x2 = bfhi(dxs[cur][c_a][l_a + 16]);
      float g1 = za / (1.f + __expf(-za));
      float g2 = zb / (1.f + __expf(-zb));
      size_t l0 = (size_t)c * CH;
      ssm_out[(base_row + l0 + l_a) * DM + d0 + c_a]      = (bf16)(s1 * g1 + x1 * Dva);
      ssm_out[(base_row + l0 + l_a + 16) * DM + d0 + c_a] = (bf16)(s2 * g2 + x2 * Dva);
    }
    if (c + 1 < LSEQ / CH) {
      dxs[nxt][pc][pl]     = (pD & 0xffffu) | (pX << 16);
      dxs[nxt][pc + 1][pl] = (pD >> 16) | (pX & 0xffff0000u);
      Bsh[nxt][pc][pl] = pB2.x;  Bsh[nxt][pc + 1][pl] = pB2.y;
      Csh[nxt][pc][pl] = pC2.x;  Csh[nxt][pc + 1][pl] = pC2.y;
      za = pza; zb = pzb;
    }
    __syncthreads();
  }
  h_final[(size_t)b * DM * NS + (size_t)d0 * NS + t] = h;
}

// ---------------------------------------------------------------------------
extern "C" void kernel_launch(void* const* d_in, const int* in_sizes, int n_in,
                              void* d_out, int out_size, void* d_ws, size_t ws_size,
                              hipStream_t stream) {
  const float* x      = (const float*)d_in[0];
  const float* h_prev = (const float*)d_in[1];
  const float* ln_g   = (const float*)d_in[2];
  const float* ln_b   = (const float*)d_in[3];
  const float* W_ig   = (const float*)d_in[4];
  const float* W_dt   = (const float*)d_in[5];
  const float* b_dt   = (const float*)d_in[6];
  const float* A_log  = (const float*)d_in[7];
  const float* W_B    = (const float*)d_in[8];
  const float* W_C    = (const float*)d_in[9];
  const float* Dvec   = (const float*)d_in[10];
  const float* W_out  = (const float*)d_in[11];

  char* ws = (char*)d_ws;
  size_t off = 0;
  auto alloc = [&](size_t bytes) -> char* {
    char* p = ws + off;
    off += (bytes + 255) & ~(size_t)255;
    return p;
  };
  bf16*  wmega_b = (bf16*)alloc((size_t)3200 * DM * 2);       // 6.25 MB
  bf16*  wstack_b= (bf16*)alloc((size_t)1152 * DM * 2);       // 2.25 MB
  bf16*  wigT_b  = (bf16*)alloc((size_t)DM * DM * 2);         // 2 MB
  bf16*  wout_b  = (bf16*)alloc((size_t)DM * DM * 2);         // 2 MB
  bf16*  xnorm_b = (bf16*)alloc((size_t)MROWS * DM * 2);      // 16 MB
  u16*   xi_w    = (u16*)alloc((size_t)MROWS * DM * 2);       // 16 MB bf16 xi (tiled-16)
  u16*   dt_w    = (u16*)alloc((size_t)MROWS * DM * 2);       // 16 MB bf16 dt (tiled-16)
  bf16*  z_bb    = (bf16*)alloc((size_t)MROWS * DM * 2);      // 16 MB (tiled-16)
  bf16*  ssm_b   = (bf16*)alloc((size_t)MROWS * DM * 2);      // 16 MB
  float* Bt      = (float*)alloc((size_t)MROWS * NS * 4);     // 0.5 MB
  float* Ct      = (float*)alloc((size_t)MROWS * NS * 4);     // 0.5 MB
  (void)ws_size; (void)in_sizes; (void)n_in; (void)out_size;

  float* out_main = (float*)d_out;
  float* out_h    = (float*)d_out + (size_t)MROWS * DM;

  // 1) fused preprocessing: casts + transpose + layernorm (1 launch)
  preproc<<<12576, 256, 0, stream>>>(W_ig, W_dt, W_B, W_C, W_out,
                                     wmega_b, wstack_b, wout_b, wigT_b,
                                     x, ln_g, ln_b, xnorm_b);

  // 2) compose: wmega[2048+e][k] = sum_d [Wdt;WB;WC][e][d] * W_ig[d][k]
  gemm_bf16<3, false><<<dim3(8, 9), 256, 0, stream>>>(wstack_b, wigT_b, DM,
      nullptr, wmega_b + (size_t)2048 * DM, nullptr, nullptr, nullptr, nullptr, nullptr);

  // 3) mega GEMM (M=8192, N=3104(pad 3200), K=1024), XCD-swizzled 1D grid:
  //    writes xi, z, dt (tiled-16 via LDS-staged dense stores), B_t, C_t
  gemm_bf16<0, true><<<1600, 256, 0, stream>>>(xnorm_b, wmega_b, DM,
      nullptr, z_bb, xi_w, dt_w, b_dt, Bt, Ct);

  // 4) selective scan + fused gate -> ssm_b, h_final
  scan_kernel<<<512, 256, 0, stream>>>(dt_w, xi_w, z_bb, Bt, Ct, A_log, h_prev,
                                       Dvec, ssm_b, out_h);

  // 5) output GEMM (M=8192, N=1024, K=1024) + residual x, XCD-swizzled
  gemm_bf16<2, true><<<512, 256, 0, stream>>>(ssm_b, wout_b, DM,
      out_main, nullptr, nullptr, nullptr, x, nullptr, nullptr);
}

// Round 11
// 309.688 us; speedup vs baseline: 1.0930x; 1.0930x over previous
//
#include <hip/hip_runtime.h>
#include <hip/hip_bf16.h>
#include <math.h>

// Problem constants (fixed by setup_inputs)
#define DM 1024          // d_model
#define NS 16            // d_state
#define BSZ 8
#define LSEQ 1024
#define MROWS (BSZ*LSEQ) // 8192 token rows
#define CH 32            // scan chunk (timesteps staged per LDS buffer)
#define ROWP 36          // padded LDS row length (words), b128-aligned
#define YSP 18           // ys_p row pad (words), b64-aligned

typedef __bf16 bf16;
typedef bf16 bf16x8 __attribute__((ext_vector_type(8)));
typedef bf16 bf16x4 __attribute__((ext_vector_type(4)));
typedef float f32x4 __attribute__((ext_vector_type(4)));
typedef float f32x2 __attribute__((ext_vector_type(2)));
typedef unsigned int u32;
typedef unsigned short u16;
typedef u32 u32x4 __attribute__((ext_vector_type(4)));

__device__ __forceinline__ void async16(const void* g, void* l) {
  __builtin_amdgcn_global_load_lds((const __attribute__((address_space(1))) void*)g,
                                   (__attribute__((address_space(3))) void*)l,
                                   16, 0, 0);
}

// packed (dt, xi) word: dt bf16 in low 16, xi bf16 in high 16
__device__ __forceinline__ float bflo(u32 u) { return __builtin_bit_cast(float, (u32)(u << 16)); }
__device__ __forceinline__ float bfhi(u32 u) { return __builtin_bit_cast(float, (u32)(u & 0xffff0000u)); }

// ---------------------------------------------------------------------------
// Fused preprocessing: weight casts + W_ig transpose + layernorm in ONE
// launch. Block ranges:
//   [0,4128)      : f32->bf16 casts (5 weight tensors, float4-granular)
//   [4128,4384)   : W_ig[:1024]^T transpose+cast (64x64 LDS tiles)
//   [4384,12576)  : layernorm, one block per token row
// ---------------------------------------------------------------------------
__global__ __launch_bounds__(256)
void preproc(const float* __restrict__ W_ig, const float* __restrict__ W_dt,
             const float* __restrict__ W_B, const float* __restrict__ W_C,
             const float* __restrict__ W_out,
             bf16* __restrict__ wmega, bf16* __restrict__ wstack,
             bf16* __restrict__ wout, bf16* __restrict__ wigT,
             const float* __restrict__ x, const float* __restrict__ ln_g,
             const float* __restrict__ ln_b, bf16* __restrict__ xnorm) {
  __shared__ float tile[64][65];     // used by transpose range only
  const int blk = blockIdx.x;
  const int t = threadIdx.x;

  if (blk < 4128) {
    int i = blk * 256 + t;           // float4 index, total 1056768
    const float* s; bf16* d; int base;
    if (i < 524288)      { s = W_ig;  d = wmega;                           base = 0; }
    else if (i < 786432) { s = W_dt;  d = wstack;                          base = 524288; }
    else if (i < 790528) { s = W_B;   d = wstack + (size_t)DM * DM;        base = 786432; }
    else if (i < 794624) { s = W_C;   d = wstack + (size_t)(DM + NS) * DM; base = 790528; }
    else                 { s = W_out; d = wout;                            base = 794624; }
    int k = i - base;
    float4 v = ((const float4*)s)[k];
    bf16x4 o;
    o.x = (bf16)v.x; o.y = (bf16)v.y; o.z = (bf16)v.z; o.w = (bf16)v.w;
    *(bf16x4*)(d + 4 * (size_t)k) = o;
  } else if (blk < 4384) {
    int tb = blk - 4128;
    const int bk = (tb & 15) * 64;
    const int bd = (tb >> 4) * 64;
    const int c4 = t & 15;
    const int r0 = t >> 4;
#pragma unroll
    for (int p = 0; p < 4; ++p) {
      int r = r0 + p * 16;
      float4 v = *(const float4*)(W_ig + (size_t)(bd + r) * 1024 + bk + c4 * 4);
      tile[r][c4 * 4 + 0] = v.x;
      tile[r][c4 * 4 + 1] = v.y;
      tile[r][c4 * 4 + 2] = v.z;
      tile[r][c4 * 4 + 3] = v.w;
    }
    __syncthreads();
#pragma unroll
    for (int p = 0; p < 4; ++p) {
      int r = r0 + p * 16;
      bf16x4 o;
      o.x = (bf16)tile[c4 * 4 + 0][r];
      o.y = (bf16)tile[c4 * 4 + 1][r];
      o.z = (bf16)tile[c4 * 4 + 2][r];
      o.w = (bf16)tile[c4 * 4 + 3][r];
      *(bf16x4*)(wigT + (size_t)(bk + r) * 1024 + bd + c4 * 4) = o;
    }
  } else {
    const size_t row = blk - 4384;
    float4 v = ((const float4*)(x + row * DM))[t];
    float s = v.x + v.y + v.z + v.w;
    float s2 = v.x*v.x + v.y*v.y + v.z*v.z + v.w*v.w;
#pragma unroll
    for (int m = 1; m < 64; m <<= 1) { s += __shfl_xor(s, m, 64); s2 += __shfl_xor(s2, m, 64); }
    __shared__ float red[8];
    int wave = t >> 6, lane = t & 63;
    if (lane == 0) { red[wave] = s; red[4 + wave] = s2; }
    __syncthreads();
    s  = red[0] + red[1] + red[2] + red[3];
    s2 = red[4] + red[5] + red[6] + red[7];
    float mu  = s * (1.f / DM);
    float var = s2 * (1.f / DM) - mu * mu;
    float inv = rsqrtf(var + 1e-5f);
    float4 gg = ((const float4*)ln_g)[t];
    float4 bb = ((const float4*)ln_b)[t];
    bf16x4 o;
    o.x = (bf16)((v.x - mu) * inv * gg.x + bb.x);
    o.y = (bf16)((v.y - mu) * inv * gg.y + bb.y);
    o.z = (bf16)((v.z - mu) * inv * gg.z + bb.z);
    o.w = (bf16)((v.w - mu) * inv * gg.w + bb.w);
    *(bf16x4*)(xnorm + row * DM + t * 4) = o;
  }
}

// ---------------------------------------------------------------------------
// MFMA bf16 GEMM: C[M,N] = A[M,K] @ W[N,K]^T. 128x128 tile.
// R8/R9-PROVEN depth-3 pipeline (90us mega): 3 LDS buffers of BK=32,
// stage-ahead 2, raw s_barrier + `s_waitcnt vmcnt(4)` per K-step (never
// drain to 0 in steady state). 48KB LDS -> 3 blocks/CU. [R10 lesson: depth-4
// at 64KB LDS halves co-residency -> MfmaUtil 24->14, FETCH +8MB. At this
// tile size OCCUPANCY beats pipeline depth -- do not deepen.]
// XOR k-chunk swizzle (0 conflicts). EPI==0 epilogue: tiled-16 output
// LDS-STAGED (R8: -20us) -- dense 2KB stores per (wave,j).
// ---------------------------------------------------------------------------
template <int EPI, bool SWZ>
__global__ __launch_bounds__(256)
void gemm_bf16(const bf16* __restrict__ A, const bf16* __restrict__ W, int K,
               float* __restrict__ out_f, bf16* __restrict__ out_b,
               u16* __restrict__ out_u1, u16* __restrict__ out_u2,
               const float* __restrict__ aux,
               float* __restrict__ out_f3, float* __restrict__ out_f4) {
  __shared__ bf16 As[3][128 * 32];
  __shared__ bf16 Bs[3][128 * 32];
  int tx, ty;
  if (SWZ) {
    int g = blockIdx.x;           // total = 8 XCD * 8 mloc * ntx
    int xcd = g & 7, slot = g >> 3;
    tx = slot >> 3;               // n-tile (n-major sweep within XCD)
    ty = xcd * 8 + (slot & 7);    // m-tile within this XCD's stripe
  } else {
    tx = blockIdx.x; ty = blockIdx.y;
  }
  const int tid  = threadIdx.x;
  const int wave = tid >> 6, lane = tid & 63;
  const int lr = lane & 15, quad = lane >> 4;
  const size_t arow = (size_t)ty * 128;
  const size_t brow = (size_t)tx * 128;
  f32x4 acc[4][4] = {};

  const int srl  = lane >> 2;          // row-local 0..15
  const int kg   = lane & 3;           // k-group 0..3
  const int srow = wave * 32 + srl;
  const int skc  = (kg ^ ((srl >> 1) & 3)) * 8;   // swizzled global k-offset
  const bf16* ag = A + (arow + srow) * (size_t)K + skc;
  const bf16* wg = W + (brow + srow) * (size_t)K + skc;

  const int soff = wave * 32 * 32;                       // stage slice
  const int ra   = (((wave >> 1) * 64) + lr) * 32 + ((quad ^ ((lr >> 1) & 3)) * 8);
  const int rb   = (((wave & 1)  * 64) + lr) * 32 + ((quad ^ ((lr >> 1) & 3)) * 8);

  bf16 *aw0 = &As[0][soff], *aw1 = &As[1][soff], *aw2 = &As[2][soff];
  bf16 *bw0 = &Bs[0][soff], *bw1 = &Bs[1][soff], *bw2 = &Bs[2][soff];
  const bf16 *ar0 = &As[0][ra], *ar1 = &As[1][ra], *ar2 = &As[2][ra];
  const bf16 *br0 = &Bs[0][rb], *br1 = &Bs[1][rb], *br2 = &Bs[2][rb];

  auto STAGE = [&](bf16* adst, bf16* bdst, int kk) {
    async16(ag + kk,                       adst);
    async16(ag + (size_t)16 * K + kk,      adst + 16 * 32);
    async16(wg + kk,                       bdst);
    async16(wg + (size_t)16 * K + kk,      bdst + 16 * 32);
  };
  auto COMPUTE = [&](const bf16* ap, const bf16* bp) {
    bf16x8 af[4], bfr[4];
#pragma unroll
    for (int i = 0; i < 4; ++i) af[i] = *(const bf16x8*)(ap + i * 16 * 32);
#pragma unroll
    for (int j = 0; j < 4; ++j) bfr[j] = *(const bf16x8*)(bp + j * 16 * 32);
#pragma unroll
    for (int i = 0; i < 4; ++i)
#pragma unroll
      for (int j = 0; j < 4; ++j)
        acc[i][j] = __builtin_amdgcn_mfma_f32_16x16x32_bf16(af[i], bfr[j], acc[i][j], 0, 0, 0);
  };

  // prologue: buffers 0 and 1 in flight (8 VMEM ops/wave)
  STAGE(aw0, bw0, 0);
  STAGE(aw1, bw1, 32);
  asm volatile("s_waitcnt vmcnt(4)" ::: "memory");   // buf0 landed (own loads)
  __builtin_amdgcn_s_barrier();                       // everyone's buf0 landed

  // K is a multiple of 32 for all call sites (K=1024, nt=32)
  for (int k0 = 0; k0 < K; k0 += 32) {
    const bool pf = (k0 + 64 < K);
    if (pf) STAGE(aw2, bw2, k0 + 64);    // into buf freed at iter-1's barrier
    COMPUTE(ar0, br0);                    // consume current buffer
    if (pf) asm volatile("s_waitcnt vmcnt(4)" ::: "memory");  // next buf landed
    else    asm volatile("s_waitcnt vmcnt(0)" ::: "memory");  // tail drain
    __builtin_amdgcn_s_barrier();
    // rotate buffer roles (register moves only)
    bf16* t0;
    t0 = aw0; aw0 = aw1; aw1 = aw2; aw2 = t0;
    t0 = bw0; bw0 = bw1; bw1 = bw2; bw2 = t0;
    const bf16* t1;
    t1 = ar0; ar0 = ar1; ar1 = ar2; ar2 = t1;
    t1 = br0; br0 = br1; br1 = br2; br2 = t1;
  }
  // After the final barrier ALL waves completed their LDS reads -> As free.

  // Epilogue. D layout (verified m89/m91): col = lane&15, row = quad*4 + reg.
  const size_t mbase = arow + (wave >> 1) * 64;
  const size_t nbase = brow + (wave & 1) * 64;
  if (EPI == 0) {
    if (nbase < 3 * DM) {
      // xi / z / dt -> tiled-16 via LDS-staged dense 2KB stores per (wave,j)
      u16* dst; size_t gbase; bool is_dt = false;
      if (nbase < DM)            { dst = out_u1;       gbase = nbase >> 4; }
      else if (nbase < 2 * DM)   { dst = (u16*)out_b;  gbase = (nbase - DM) >> 4; }
      else                       { dst = out_u2;       gbase = (nbase - 2 * DM) >> 4; is_dt = true; }
      bf16* lds_ep = &As[0][0] + (size_t)wave * 1024;   // 2KB private slice
#pragma unroll
      for (int j = 0; j < 4; ++j) {
#pragma unroll
        for (int i = 0; i < 4; ++i)
#pragma unroll
          for (int r = 0; r < 4; ++r) {
            float v = acc[i][j][r];
            if (is_dt) {
              float tt = v + aux[nbase - 2 * DM + j * 16 + lr];
              v = (tt > 20.f) ? tt : __logf(1.f + __expf(tt));
            }
            lds_ep[(i * 16 + quad * 4 + r) * 16 + lr] = (bf16)v;
          }
        u32x4 v0 = *(u32x4*)&lds_ep[lane * 16];
        u32x4 v1 = *(u32x4*)&lds_ep[lane * 16 + 8];
        size_t off = ((gbase + j) * (size_t)MROWS + mbase + lane) * 16;
        *(u32x4*)&dst[off]     = v0;
        *(u32x4*)&dst[off + 8] = v1;
      }
    } else if (nbase < 3 * DM + 2 * NS) {   // B/C region (j==0 -> B, j==1 -> C)
#pragma unroll
      for (int i = 0; i < 4; ++i)
#pragma unroll
        for (int r = 0; r < 4; ++r) {
          size_t m = mbase + i * 16 + quad * 4 + r;
          out_f3[m * NS + lr] = acc[i][0][r];
          out_f4[m * NS + lr] = acc[i][1][r];
        }
    } // else: garbage pad columns, discard
  } else {
#pragma unroll
    for (int i = 0; i < 4; ++i)
#pragma unroll
      for (int j = 0; j < 4; ++j)
#pragma unroll
        for (int r = 0; r < 4; ++r) {
          size_t m = mbase + i * 16 + quad * 4 + r;
          size_t n = nbase + j * 16 + lr;
          float v = acc[i][j][r];
          if (EPI == 2) {
            out_f[m * DM + n] = v + aux[m * DM + n];
          } else {
            out_b[m * (size_t)DM + n] = (bf16)v;
          }
        }
  }
}

// ---------------------------------------------------------------------------
// Selective scan + fused gate, v8 (kept from R10 -- neutral-to-positive).
// Tiled-16 dt/xi/z + ys_p LDS n-reduction. Paired staging loads (dt/xi as
// one u32 each, B/C as f32x2); phase-2 reads ys_p rows as b64 (YSP=18 pad).
// ---------------------------------------------------------------------------
__global__ __launch_bounds__(256)
void scan_kernel(const u16* __restrict__ dt_b, const u16* __restrict__ xi_b,
                 const bf16* __restrict__ z_b,
                 const float* __restrict__ B_t, const float* __restrict__ C_t,
                 const float* __restrict__ A_log, const float* __restrict__ h_prev,
                 const float* __restrict__ Dvec,
                 bf16* __restrict__ ssm_out, float* __restrict__ h_final) {
  const int blk = blockIdx.x;        // 512 blocks
  const int b = blk >> 6;
  const int g = blk & 63;            // channel group
  const int d0 = g * 16;
  const int t = threadIdx.x;
  const int n = t & 15, dl = t >> 4;     // compute role: channel dl, state n
  const int d = d0 + dl;
  const float Ac2 = -__expf(A_log[d * NS + n]) * 1.44269504f;  // fold log2e
  float h = h_prev[(size_t)b * DM * NS + (size_t)d * NS + n];

  __shared__ u32   dxs[2][16][ROWP];   // packed (dt lo, xi hi): [chan][l]
  __shared__ float Bsh[2][16][ROWP];   // [n][l]
  __shared__ float Csh[2][16][ROWP];   // [n][l]
  __shared__ float ys_p[CH][16][YSP];  // per-lane h*C partials: [l][chan][n]

  const size_t base_row = (size_t)b * LSEQ;
  const size_t base16 = ((size_t)g * MROWS + base_row) * 16;
  // staging role (paired): thread t covers elements e0=2t, e1=2t+1 of the
  // 512-element chunk: row pl = t>>3, chans pc, pc+1 (pc even).
  const int pl = t >> 3, pc = (2 * t) & 15;
  // output role: channel c_a, rows l_a and l_a+16
  const int l_a = t >> 4, c_a = t & 15;
  const float Dva = Dvec[d0 + c_a];

  // --- stage chunk 0 ---
  {
    u32 D = ((const u32*)(dt_b + base16))[t];
    u32 X = ((const u32*)(xi_b + base16))[t];
    dxs[0][pc][pl]     = (D & 0xffffu) | (X << 16);
    dxs[0][pc + 1][pl] = (D >> 16) | (X & 0xffff0000u);
    size_t gB = base_row * NS;
    f32x2 B2 = ((const f32x2*)(B_t + gB))[t];
    f32x2 C2 = ((const f32x2*)(C_t + gB))[t];
    Bsh[0][pc][pl] = B2.x;  Bsh[0][pc + 1][pl] = B2.y;
    Csh[0][pc][pl] = C2.x;  Csh[0][pc + 1][pl] = C2.y;
  }
  float za = (float)z_b[base16 + t];
  float zb = (float)z_b[base16 + 256 + t];
  __syncthreads();

  for (int c = 0; c < LSEQ / CH; ++c) {
    const int cur = c & 1, nxt = cur ^ 1;
    // prefetch next chunk into registers (overlaps compute below)
    u32 pD, pX; f32x2 pB2, pC2; float pza, pzb;
    if (c + 1 < LSEQ / CH) {
      size_t off = base16 + (size_t)(c + 1) * (CH * 16);
      pD = ((const u32*)(dt_b + off))[t];
      pX = ((const u32*)(xi_b + off))[t];
      pza = (float)z_b[off + t]; pzb = (float)z_b[off + 256 + t];
      size_t gB = (base_row + (size_t)(c + 1) * CH) * NS;
      pB2 = ((const f32x2*)(B_t + gB))[t];
      pC2 = ((const f32x2*)(C_t + gB))[t];
    }
    // hot loop: 4 steps per LDS read batch; serial chain = fma only
#pragma unroll
    for (int l4 = 0; l4 < CH; l4 += 4) {
      u32x4 dx4 = *(const u32x4*)&dxs[cur][dl][l4];   // broadcast over n-lanes
      f32x4 b4  = *(const f32x4*)&Bsh[cur][n][l4];
      f32x4 c4  = *(const f32x4*)&Csh[cur][n][l4];
#pragma unroll
      for (int i = 0; i < 4; ++i) {
        float dtv = bflo(dx4[i]), xiv = bfhi(dx4[i]);
        float a = __builtin_amdgcn_exp2f(dtv * Ac2);
        h = fmaf(a, h, (dtv * xiv) * b4[i]);
        ys_p[l4 + i][dl][n] = h * c4[i];
      }
    }
    __syncthreads();
    // phase 2: sum over n (b64 reads), gate, store
    {
      const f32x2* r1 = (const f32x2*)&ys_p[l_a][c_a][0];
      const f32x2* r2 = (const f32x2*)&ys_p[l_a + 16][c_a][0];
      float s1 = 0.f, s2 = 0.f;
#pragma unroll
      for (int k = 0; k < 8; ++k) {
        f32x2 v1 = r1[k], v2 = r2[k];
        s1 += v1.x + v1.y;
        s2 += v2.x + v2.y;
      }
      float x1 = bfhi(dxs[cur][c_a][l_a]);
      float x2 = bfhi(dxs[cur][c_a][l_a + 16]);
      float g1 = za / (1.f + __expf(-za));
      float g2 = zb / (1.f + __expf(-zb));
      size_t l0 = (size_t)c * CH;
      ssm_out[(base_row + l0 + l_a) * DM + d0 + c_a]      = (bf16)(s1 * g1 + x1 * Dva);
      ssm_out[(base_row + l0 + l_a + 16) * DM + d0 + c_a] = (bf16)(s2 * g2 + x2 * Dva);
    }
    if (c + 1 < LSEQ / CH) {
      dxs[nxt][pc][pl]     = (pD & 0xffffu) | (pX << 16);
      dxs[nxt][pc + 1][pl] = (pD >> 16) | (pX & 0xffff0000u);
      Bsh[nxt][pc][pl] = pB2.x;  Bsh[nxt][pc + 1][pl] = pB2.y;
      Csh[nxt][pc][pl] = pC2.x;  Csh[nxt][pc + 1][pl] = pC2.y;
      za = pza; zb = pzb;
    }
    __syncthreads();
  }
  h_final[(size_t)b * DM * NS + (size_t)d0 * NS + t] = h;
}

// ---------------------------------------------------------------------------
extern "C" void kernel_launch(void* const* d_in, const int* in_sizes, int n_in,
                              void* d_out, int out_size, void* d_ws, size_t ws_size,
                              hipStream_t stream) {
  const float* x      = (const float*)d_in[0];
  const float* h_prev = (const float*)d_in[1];
  const float* ln_g   = (const float*)d_in[2];
  const float* ln_b   = (const float*)d_in[3];
  const float* W_ig   = (const float*)d_in[4];
  const float* W_dt   = (const float*)d_in[5];
  const float* b_dt   = (const float*)d_in[6];
  const float* A_log  = (const float*)d_in[7];
  const float* W_B    = (const float*)d_in[8];
  const float* W_C    = (const float*)d_in[9];
  const float* Dvec   = (const float*)d_in[10];
  const float* W_out  = (const float*)d_in[11];

  char* ws = (char*)d_ws;
  size_t off = 0;
  auto alloc = [&](size_t bytes) -> char* {
    char* p = ws + off;
    off += (bytes + 255) & ~(size_t)255;
    return p;
  };
  bf16*  wmega_b = (bf16*)alloc((size_t)3200 * DM * 2);       // 6.25 MB
  bf16*  wstack_b= (bf16*)alloc((size_t)1152 * DM * 2);       // 2.25 MB
  bf16*  wigT_b  = (bf16*)alloc((size_t)DM * DM * 2);         // 2 MB
  bf16*  wout_b  = (bf16*)alloc((size_t)DM * DM * 2);         // 2 MB
  bf16*  xnorm_b = (bf16*)alloc((size_t)MROWS * DM * 2);      // 16 MB
  u16*   xi_w    = (u16*)alloc((size_t)MROWS * DM * 2);       // 16 MB bf16 xi (tiled-16)
  u16*   dt_w    = (u16*)alloc((size_t)MROWS * DM * 2);       // 16 MB bf16 dt (tiled-16)
  bf16*  z_bb    = (bf16*)alloc((size_t)MROWS * DM * 2);      // 16 MB (tiled-16)
  bf16*  ssm_b   = (bf16*)alloc((size_t)MROWS * DM * 2);      // 16 MB
  float* Bt      = (float*)alloc((size_t)MROWS * NS * 4);     // 0.5 MB
  float* Ct      = (float*)alloc((size_t)MROWS * NS * 4);     // 0.5 MB
  (void)ws_size; (void)in_sizes; (void)n_in; (void)out_size;

  float* out_main = (float*)d_out;
  float* out_h    = (float*)d_out + (size_t)MROWS * DM;

  // 1) fused preprocessing: casts + transpose + layernorm (1 launch)
  preproc<<<12576, 256, 0, stream>>>(W_ig, W_dt, W_B, W_C, W_out,
                                     wmega_b, wstack_b, wout_b, wigT_b,
                                     x, ln_g, ln_b, xnorm_b);

  // 2) compose: wmega[2048+e][k] = sum_d [Wdt;WB;WC][e][d] * W_ig[d][k]
  gemm_bf16<3, false><<<dim3(8, 9), 256, 0, stream>>>(wstack_b, wigT_b, DM,
      nullptr, wmega_b + (size_t)2048 * DM, nullptr, nullptr, nullptr, nullptr, nullptr);

  // 3) mega GEMM (M=8192, N=3104(pad 3200), K=1024), XCD-swizzled 1D grid:
  //    writes xi, z, dt (tiled-16 via LDS-staged dense stores), B_t, C_t
  gemm_bf16<0, true><<<1600, 256, 0, stream>>>(xnorm_b, wmega_b, DM,
      nullptr, z_bb, xi_w, dt_w, b_dt, Bt, Ct);

  // 4) selective scan + fused gate -> ssm_b, h_final
  scan_kernel<<<512, 256, 0, stream>>>(dt_w, xi_w, z_bb, Bt, Ct, A_log, h_prev,
                                       Dvec, ssm_b, out_h);

  // 5) output GEMM (M=8192, N=1024, K=1024) + residual x, XCD-swizzled
  gemm_bf16<2, true><<<512, 256, 0, stream>>>(ssm_b, wout_b, DM,
      out_main, nullptr, nullptr, nullptr, x, nullptr, nullptr);
}